// Round 1
// baseline (402.276 us; speedup 1.0000x reference)
//
#include <hip/hip_runtime.h>
#include <stdint.h>

typedef _Float16 half8 __attribute__((ext_vector_type(8)));
typedef float float4v __attribute__((ext_vector_type(4)));

__host__ __device__ inline void tf2x32(uint32_t k0, uint32_t k1,
                                       uint32_t x0, uint32_t x1,
                                       uint32_t* o0, uint32_t* o1) {
  const uint32_t ks2 = k0 ^ k1 ^ 0x1BD11BDAu;
#define ROTL(v, s) (((v) << (s)) | ((v) >> (32 - (s))))
#define RND(r) do { x0 += x1; x1 = ROTL(x1, r); x1 ^= x0; } while (0)
  x0 += k0; x1 += k1;
  RND(13); RND(15); RND(26); RND(6);
  x0 += k1; x1 += ks2 + 1u;
  RND(17); RND(29); RND(16); RND(24);
  x0 += ks2; x1 += k0 + 2u;
  RND(13); RND(15); RND(26); RND(6);
  x0 += k0; x1 += k1 + 3u;
  RND(17); RND(29); RND(16); RND(24);
  x0 += k1; x1 += ks2 + 4u;
  RND(13); RND(15); RND(26); RND(6);
  x0 += ks2; x1 += k0 + 5u;
  *o0 = x0; *o1 = x1;
#undef RND
#undef ROTL
}

__device__ inline bool drop_keep(uint32_t k0, uint32_t k1, uint32_t idx) {
  uint32_t o0, o1;
  tf2x32(k0, k1, 0u, idx, &o0, &o1);
  uint32_t bits = o0 ^ o1;
  float u = __uint_as_float((bits >> 9) | 0x3f800000u) - 1.0f;
  return u < 0.4f;
}

// XCD-owned slotted-CSR fill (R9-proven).
__global__ void k_fill2(const int* __restrict__ row, const int* __restrict__ col,
                        int* __restrict__ cnt, uint16_t* __restrict__ cs,
                        int e, int rows_per_xcd) {
  const int owner = blockIdx.x & 7;
  const int i = (blockIdx.x >> 3) * 256 + threadIdx.x;
  if (i < e) {
    int r = row[i];
    if (r / rows_per_xcd == owner) {
      int pos = atomicAdd(&cnt[r], 1);
      if (pos < 64) cs[(r << 6) + pos] = (uint16_t)col[i];
    }
  }
}

// layer-0 dropout + dis + slot padding (to multiple of 8) + W -> f16 W^T.
__global__ void k_drop(const float* __restrict__ x, const int* __restrict__ cnt,
                       uint16_t* __restrict__ cs, float* __restrict__ dis,
                       _Float16* __restrict__ y, _Float16* __restrict__ ys,
                       _Float16* __restrict__ ysb, uint32_t k0, uint32_t k1,
                       int n, int nd,
                       const float* __restrict__ W0, const float* __restrict__ W1,
                       const float* __restrict__ W2, _Float16* __restrict__ wh) {
  int i = blockIdx.x * 256 + threadIdx.x;
  if (i < 20480) {
    int d = i;
    if (d < 8192) {
      int o = d >> 7, k = d & 127;
      wh[d] = (_Float16)W0[k * 64 + o];
    } else if (d < 16384) {
      int d1 = d - 8192, o = d1 >> 7, k = d1 & 127;
      wh[d] = (_Float16)W1[k * 64 + o];
    } else {
      int d2 = d - 16384, o = d2 >> 7, k = d2 & 127;
      wh[d] = (_Float16)W2[k * 32 + o];
    }
  }
  if (i < 64) {                        // zero dummy gather rows (index n)
    ys[((size_t)n << 6) + i]  = (_Float16)0.f;
    ysb[((size_t)n << 6) + i] = (_Float16)0.f;
  }
  if (i < nd) {
    const int r = i >> 6;
    const int t = i & 63;
    const int d = cnt[r];
    const float dis_r = (d > 0) ? rsqrtf((float)d) : 0.0f;
    float v = drop_keep(k0, k1, (uint32_t)i) ? x[i] * 2.5f : 0.0f;
    y[i]  = (_Float16)v;
    ys[i] = (_Float16)(dis_r * v);
    if (t == 0) dis[r] = dis_r;
    const int cn = d < 64 ? d : 64;
    const int rnd = (cn + 7) & ~7;
    if (t >= cn && t < rnd) cs[(r << 6) + t] = (uint16_t)n;  // pad slot
  }
}

// Issue T batches of 8 edges' gather loads into hv[0..T) (compile-time
// indexed -> registers). Lane l = 8*g + sub loads bytes [sub*16, sub*16+16)
// of edge g's row. NO consumption here — caller issues all rows first.
template<int T>
__device__ __forceinline__ void issueT(int idx_all, int rnd, int g, int sub,
                                       const _Float16* __restrict__ ysg,
                                       uint32_t dummy, half8 hv[8]) {
  #pragma unroll
  for (int j = 0; j < T; ++j) {
    int sh = __shfl(idx_all, j * 8 + g, 64);          // slot (j*8+g)'s index
    uint32_t c = (j * 8 < rnd) ? (uint32_t)(sh & 0xffff) : dummy;  // uniform sel
    hv[j] = *(const half8*)((const char*)ysg + (c << 7) + (sub << 4));
  }
}

template<int T>
__device__ __forceinline__ void consumeT(const half8 hv[8], float acc[8]) {
  #pragma unroll
  for (int j = 0; j < T; ++j)
    #pragma unroll
    for (int k = 0; k < 8; ++k) acc[k] += (float)hv[j][k];
}

// Fused conv. Block = 4 waves, 16 rows (50000 = 3125*16 exact).
// Phase 1a: ALL 4 rows' gather loads issued back-to-back into a unified
//   half8 hv[4][8] register block (up to 32 outstanding 16B loads/wave) —
//   ONE gather-latency exposure per wave instead of four (R15 change).
// Phase 1b: per-row consume + 3-step shfl_xor halving butterfly (keep/send
//   cndmask pairs -> fixed register result, no runtime-indexed arrays, no LDS,
//   no barriers). Lane t ends with feature (t&7)*8+(t>>3)'s full sum and
//   writes that permuted xp column (covers 0..63, 2 lanes/bank = free).
//   Accumulation order per row is identical to R14 -> bitwise-same output.
// Phase 2: MFMA 16x16x32_f16; A = [y|p] LDS tile, B = global f16 W^T.
// Phase 3: epilogue: +bias, relu, next-layer dropout; dual store y / ys.
template<int COUT, bool RELU, bool DROPN, bool WBF>
__global__ __launch_bounds__(256, 6) void k_conv(
    const _Float16* __restrict__ yg, const _Float16* __restrict__ ysg,
    const int* __restrict__ cnt, const uint16_t* __restrict__ cs,
    const float* __restrict__ dis, const _Float16* __restrict__ wt,
    const float* __restrict__ b, float* __restrict__ outf,
    _Float16* __restrict__ outb, _Float16* __restrict__ outs,
    uint32_t nk0, uint32_t nk1, int n) {
  constexpr int R  = 16;
  constexpr int TS = 136;
  __shared__ __align__(16) _Float16 xp[R][TS];

  const int wave = threadIdx.x >> 6;
  const int t    = threadIdx.x & 63;
  const int row0 = blockIdx.x * R;
  const int g    = t >> 3;
  const int sub  = t & 7;
  const uint32_t dummy = (uint32_t)n;

  // ---- Phase 1 prologue: all 4 rows' loads issued up front ----
  int      idxs[4], ds4[4];
  float    dv4[4];
  _Float16 ygv[4];
  #pragma unroll
  for (int i = 0; i < 4; ++i) {
    int r = row0 + wave * 4 + i;
    r = r < n ? r : n - 1;                       // clamp (grid is exact anyway)
    idxs[i] = cs[(r << 6) + t];                  // coalesced 128B slot line
    ds4[i]  = cnt[r];                            // wave-uniform
    dv4[i]  = dis[r];
    ygv[i]  = yg[(uint32_t)(r << 6) + t];
  }

  // ---- Phase 1a: issue ALL rows' gathers (max MLP, single latency wall) ----
  half8 hv[4][8];
  #pragma unroll
  for (int i = 0; i < 4; ++i) {
    const int cn  = ds4[i] < 64 ? ds4[i] : 64;
    const int rnd = (cn + 7) & ~7;               // wave-uniform branch
    if (rnd <= 16)      issueT<2>(idxs[i], rnd, g, sub, ysg, dummy, hv[i]);
    else if (rnd <= 32) issueT<4>(idxs[i], rnd, g, sub, ysg, dummy, hv[i]);
    else                issueT<8>(idxs[i], rnd, g, sub, ysg, dummy, hv[i]);
  }
  __builtin_amdgcn_sched_barrier(0);             // keep loads above consumes

  // ---- Phase 1b: per-row consume + butterfly reduction ----
  #pragma unroll
  for (int i = 0; i < 4; ++i) {
    const int cn  = ds4[i] < 64 ? ds4[i] : 64;
    const int rnd = (cn + 7) & ~7;
    float acc[8] = {0.f, 0.f, 0.f, 0.f, 0.f, 0.f, 0.f, 0.f};
    if (rnd <= 16)      consumeT<2>(hv[i], acc);
    else if (rnd <= 32) consumeT<4>(hv[i], acc);
    else                consumeT<8>(hv[i], acc);

    // halving butterfly over g bits (lane bits 3..5): lane ends with the
    // full sum of acc element g. keep/send selected by g's bit per step.
    const bool b0 = (g & 1), b1 = (g & 2), b2 = (g & 4);
    float a4[4], a2[2], v;
    #pragma unroll
    for (int m = 0; m < 4; ++m) {
      float keep = b0 ? acc[2 * m + 1] : acc[2 * m];
      float send = b0 ? acc[2 * m]     : acc[2 * m + 1];
      a4[m] = keep + __shfl_xor(send, 8, 64);
    }
    #pragma unroll
    for (int m = 0; m < 2; ++m) {
      float keep = b1 ? a4[2 * m + 1] : a4[2 * m];
      float send = b1 ? a4[2 * m]     : a4[2 * m + 1];
      a2[m] = keep + __shfl_xor(send, 16, 64);
    }
    {
      float keep = b2 ? a2[1] : a2[0];
      float send = b2 ? a2[0] : a2[1];
      v = keep + __shfl_xor(send, 32, 64);
    }
    const int rl = wave * 4 + i;
    xp[rl][t]                    = ygv[i];
    xp[rl][64 + (sub * 8 + g)]   = (_Float16)(-dv4[i] * v);
  }
  __syncthreads();

  // ---- Phase 2: MFMA (B fragments from global W^T) ----
  constexpr int NW = COUT / 16;
  const int nn   = t & 15;
  const int quad = t >> 4;
  if (wave < NW) {
    const int colg = wave * 16 + nn;
    float4v acc = {0.f, 0.f, 0.f, 0.f};
    #pragma unroll
    for (int ks = 0; ks < 4; ++ks) {
      half8 a  = *(const half8*)&xp[nn][quad * 8 + 32 * ks];
      half8 bb = *(const half8*)&wt[(size_t)colg * 128 + quad * 8 + 32 * ks];
      acc = __builtin_amdgcn_mfma_f32_16x16x32_f16(a, bb, acc, 0, 0, 0);
    }
    // ---- Phase 3: epilogue ----
    const float bias = b[colg];
    #pragma unroll
    for (int rg = 0; rg < 4; ++rg) {
      const int rl = quad * 4 + rg;
      const int rr = row0 + rl;
      if (rr < n) {
        float v = acc[rg] + bias;
        if (RELU) v = fmaxf(v, 0.0f);
        if (DROPN) {
          if (drop_keep(nk0, nk1, (uint32_t)(rr * 64 + colg))) v *= 2.5f;
          else v = 0.0f;
        }
        if (WBF) {
          outb[(size_t)rr * COUT + colg] = (_Float16)v;
          outs[(size_t)rr * COUT + colg] = (_Float16)(dis[rr] * v);
        } else {
          outf[(size_t)rr * COUT + colg] = v;
        }
      }
    }
  }
}

extern "C" void kernel_launch(void* const* d_in, const int* in_sizes, int n_in,
                              void* d_out, int out_size, void* d_ws, size_t ws_size,
                              hipStream_t stream) {
  const float* x   = (const float*)d_in[0];
  const int*   ei  = (const int*)d_in[1];
  const float* W0  = (const float*)d_in[2];
  const float* b0  = (const float*)d_in[3];
  const float* W1f = (const float*)d_in[4];
  const float* b1  = (const float*)d_in[5];
  const float* W2  = (const float*)d_in[6];
  const float* b2  = (const float*)d_in[7];
  float* out = (float*)d_out;

  const int n = in_sizes[0] / 64;   // 50000
  const int e = in_sizes[1] / 2;    // 800000
  const int* row = ei;
  const int* col = ei + e;

  size_t off = 0;
  auto carve = [&](size_t elems) {   // elems in int32 units, 1KB-aligned
    size_t o = off;
    off += (elems + 255) & ~(size_t)255;
    return o;
  };
  int* base = (int*)d_ws;
  int*      cnt = base + carve(n);
  float*    dis = (float*)(base + carve(n));
  uint16_t* cs  = (uint16_t*)(base + carve((size_t)n * 32));       // n*64 u16
  _Float16* ya  = (_Float16*)(base + carve((size_t)n * 32));       // n*64 f16
  _Float16* ysa = (_Float16*)(base + carve((size_t)(n + 1) * 32)); // (n+1)*64 f16
  _Float16* yb  = (_Float16*)(base + carve((size_t)n * 32));
  _Float16* ysb = (_Float16*)(base + carve((size_t)(n + 1) * 32));
  _Float16* wh  = (_Float16*)(base + carve(10240));                // 20480 f16
  (void)ws_size;
  _Float16* wh0 = wh;            // [64][128]
  _Float16* wh1 = wh + 8192;     // [64][128]
  _Float16* wh2 = wh + 16384;    // [32][128]

  // dropout keys: fold_in(jax.random.key(1), i) = threefry2x32([0,1],[0,i])
  uint32_t dk[3][2];
  for (uint32_t i = 0; i < 3; ++i) tf2x32(0u, 1u, 0u, i, &dk[i][0], &dk[i][1]);

  hipMemsetAsync(cnt, 0, (size_t)n * 4, stream);

  const int nchunk = (e + 255) / 256;    // 3125
  const int bd = ((n * 64) + 255) / 256; // 12500
  const int bc = (n + 15) / 16;          // 3125
  const int rpx = (n + 7) / 8;           // rows per XCD slice (6250)

  k_fill2<<<nchunk * 8, 256, 0, stream>>>(row, col, cnt, cs, e, rpx);
  k_drop<<<bd, 256, 0, stream>>>(x, cnt, cs, dis, ya, ysa, ysb,
                                 dk[0][0], dk[0][1], n, n * 64,
                                 W0, W1f, W2, wh);

  k_conv<64, true,  true,  true ><<<bc, 256, 0, stream>>>(
      ya, ysa, cnt, cs, dis, wh0, b0, nullptr, yb, ysb, dk[1][0], dk[1][1], n);
  k_conv<64, true,  true,  true ><<<bc, 256, 0, stream>>>(
      yb, ysb, cnt, cs, dis, wh1, b1, nullptr, ya, ysa, dk[2][0], dk[2][1], n);
  k_conv<32, false, false, false><<<bc, 256, 0, stream>>>(
      ya, ysa, cnt, cs, dis, wh2, b2, out, nullptr, nullptr, 0u, 0u, n);
}

// Round 2
// 204.419 us; speedup vs baseline: 1.9679x; 1.9679x over previous
//
#include <hip/hip_runtime.h>
#include <stdint.h>

typedef _Float16 half8 __attribute__((ext_vector_type(8)));
typedef float float4v __attribute__((ext_vector_type(4)));

__host__ __device__ inline void tf2x32(uint32_t k0, uint32_t k1,
                                       uint32_t x0, uint32_t x1,
                                       uint32_t* o0, uint32_t* o1) {
  const uint32_t ks2 = k0 ^ k1 ^ 0x1BD11BDAu;
#define ROTL(v, s) (((v) << (s)) | ((v) >> (32 - (s))))
#define RND(r) do { x0 += x1; x1 = ROTL(x1, r); x1 ^= x0; } while (0)
  x0 += k0; x1 += k1;
  RND(13); RND(15); RND(26); RND(6);
  x0 += k1; x1 += ks2 + 1u;
  RND(17); RND(29); RND(16); RND(24);
  x0 += ks2; x1 += k0 + 2u;
  RND(13); RND(15); RND(26); RND(6);
  x0 += k0; x1 += k1 + 3u;
  RND(17); RND(29); RND(16); RND(24);
  x0 += k1; x1 += ks2 + 4u;
  RND(13); RND(15); RND(26); RND(6);
  x0 += ks2; x1 += k0 + 5u;
  *o0 = x0; *o1 = x1;
#undef RND
#undef ROTL
}

__device__ inline bool drop_keep(uint32_t k0, uint32_t k1, uint32_t idx) {
  uint32_t o0, o1;
  tf2x32(k0, k1, 0u, idx, &o0, &o1);
  uint32_t bits = o0 ^ o1;
  float u = __uint_as_float((bits >> 9) | 0x3f800000u) - 1.0f;
  return u < 0.4f;
}

// XCD-owned slotted-CSR fill (R9-proven).
__global__ void k_fill2(const int* __restrict__ row, const int* __restrict__ col,
                        int* __restrict__ cnt, uint16_t* __restrict__ cs,
                        int e, int rows_per_xcd) {
  const int owner = blockIdx.x & 7;
  const int i = (blockIdx.x >> 3) * 256 + threadIdx.x;
  if (i < e) {
    int r = row[i];
    if (r / rows_per_xcd == owner) {
      int pos = atomicAdd(&cnt[r], 1);
      if (pos < 64) cs[(r << 6) + pos] = (uint16_t)col[i];
    }
  }
}

// layer-0 dropout + dis + slot padding (to multiple of 8) + W -> f16 W^T.
__global__ void k_drop(const float* __restrict__ x, const int* __restrict__ cnt,
                       uint16_t* __restrict__ cs, float* __restrict__ dis,
                       _Float16* __restrict__ y, _Float16* __restrict__ ys,
                       _Float16* __restrict__ ysb, uint32_t k0, uint32_t k1,
                       int n, int nd,
                       const float* __restrict__ W0, const float* __restrict__ W1,
                       const float* __restrict__ W2, _Float16* __restrict__ wh) {
  int i = blockIdx.x * 256 + threadIdx.x;
  if (i < 20480) {
    int d = i;
    if (d < 8192) {
      int o = d >> 7, k = d & 127;
      wh[d] = (_Float16)W0[k * 64 + o];
    } else if (d < 16384) {
      int d1 = d - 8192, o = d1 >> 7, k = d1 & 127;
      wh[d] = (_Float16)W1[k * 64 + o];
    } else {
      int d2 = d - 16384, o = d2 >> 7, k = d2 & 127;
      wh[d] = (_Float16)W2[k * 32 + o];
    }
  }
  if (i < 64) {                        // zero dummy gather rows (index n)
    ys[((size_t)n << 6) + i]  = (_Float16)0.f;
    ysb[((size_t)n << 6) + i] = (_Float16)0.f;
  }
  if (i < nd) {
    const int r = i >> 6;
    const int t = i & 63;
    const int d = cnt[r];
    const float dis_r = (d > 0) ? rsqrtf((float)d) : 0.0f;
    float v = drop_keep(k0, k1, (uint32_t)i) ? x[i] * 2.5f : 0.0f;
    y[i]  = (_Float16)v;
    ys[i] = (_Float16)(dis_r * v);
    if (t == 0) dis[r] = dis_r;
    const int cn = d < 64 ? d : 64;
    const int rnd = (cn + 7) & ~7;
    if (t >= cn && t < rnd) cs[(r << 6) + t] = (uint16_t)n;  // pad slot
  }
}

// One batch-group of T*8 edges starting at slot jb*8: issue T half8 loads,
// then consume into acc in ascending-j order (same FP order as R14).
// Lane l = 8*g + sub loads bytes [sub*16, sub*16+16) of edge (jb+j)*8+g's row.
// Register peak: hv[T] <= 16 VGPRs (T capped at 4 by callers).
template<int T>
__device__ __forceinline__ void gatherT(int idx_all, int rnd, int jb, int g,
                                        int sub,
                                        const _Float16* __restrict__ ysg,
                                        uint32_t dummy, float acc[8]) {
  half8 hv[T];
  #pragma unroll
  for (int j = 0; j < T; ++j) {
    int sh = __shfl(idx_all, (jb + j) * 8 + g, 64);   // slot ((jb+j)*8+g)'s index
    uint32_t c = ((jb + j) * 8 < rnd) ? (uint32_t)(sh & 0xffff) : dummy;
    hv[j] = *(const half8*)((const char*)ysg + (c << 7) + (sub << 4));
  }
  #pragma unroll
  for (int j = 0; j < T; ++j)
    #pragma unroll
    for (int k = 0; k < 8; ++k) acc[k] += (float)hv[j][k];
}

// Fused conv. Block = 16 waves (1024 threads), 16 rows, ONE ROW PER WAVE
// (R16 change: TLP instead of per-wave ILP after the R15 spill disaster).
//   - launch_bounds(1024, 8): 2 blocks/CU = 32 waves/CU (HW max), VGPR cap 64.
//   - Per wave: 1 gather-latency wall (was 4), register peak ~45 VGPR (hv[4]
//     max: degrees > 32 — Poisson(16) tail, ~10 rows total — take two
//     sequential T=4 passes into the same acc, identical FP order).
// Phase 1: 8-edges-per-dwordx4 gather + 3-step shfl_xor halving butterfly
//   (keep/send cndmask pairs -> fixed registers, no LDS, no barriers).
//   Lane t ends with feature (t&7)*8+(t>>3)'s full sum and writes that
//   permuted xp column (covers 0..63, 2 lanes/bank = free).
// Phase 2: MFMA 16x16x32_f16 on waves 0..NW-1; A = [y|p] LDS tile,
//   B = global f16 W^T.
// Phase 3: epilogue: +bias, relu, next-layer dropout; dual store y / ys.
template<int COUT, bool RELU, bool DROPN, bool WBF>
__global__ __launch_bounds__(1024, 8) void k_conv(
    const _Float16* __restrict__ yg, const _Float16* __restrict__ ysg,
    const int* __restrict__ cnt, const uint16_t* __restrict__ cs,
    const float* __restrict__ dis, const _Float16* __restrict__ wt,
    const float* __restrict__ b, float* __restrict__ outf,
    _Float16* __restrict__ outb, _Float16* __restrict__ outs,
    uint32_t nk0, uint32_t nk1, int n) {
  constexpr int R  = 16;
  constexpr int TS = 136;
  __shared__ __align__(16) _Float16 xp[R][TS];

  const int wave = threadIdx.x >> 6;     // 0..15 == local row
  const int t    = threadIdx.x & 63;
  const int row0 = blockIdx.x * R;
  const int g    = t >> 3;
  const int sub  = t & 7;
  const uint32_t dummy = (uint32_t)n;

  // ---- Phase 1: this wave's single row ----
  {
    int r = row0 + wave;
    r = r < n ? r : n - 1;                       // clamp (grid is exact anyway)
    const int      idx_all = cs[(r << 6) + t];   // coalesced 128B slot line
    const int      d       = cnt[r];             // wave-uniform
    const float    dv      = dis[r];
    const _Float16 ygv     = yg[(uint32_t)(r << 6) + t];

    const int cn  = d < 64 ? d : 64;
    const int rnd = (cn + 7) & ~7;               // wave-uniform branch
    float acc[8] = {0.f, 0.f, 0.f, 0.f, 0.f, 0.f, 0.f, 0.f};
    if (rnd <= 16) {
      gatherT<2>(idx_all, rnd, 0, g, sub, ysg, dummy, acc);
    } else if (rnd <= 32) {
      gatherT<4>(idx_all, rnd, 0, g, sub, ysg, dummy, acc);
    } else {                                     // rare tail (deg > 32)
      gatherT<4>(idx_all, rnd, 0, g, sub, ysg, dummy, acc);
      gatherT<4>(idx_all, rnd, 4, g, sub, ysg, dummy, acc);
    }

    // halving butterfly over g bits (lane bits 3..5): lane ends with the
    // full sum of acc element g. keep/send selected by g's bit per step.
    const bool b0 = (g & 1), b1 = (g & 2), b2 = (g & 4);
    float a4[4], a2[2], v;
    #pragma unroll
    for (int m = 0; m < 4; ++m) {
      float keep = b0 ? acc[2 * m + 1] : acc[2 * m];
      float send = b0 ? acc[2 * m]     : acc[2 * m + 1];
      a4[m] = keep + __shfl_xor(send, 8, 64);
    }
    #pragma unroll
    for (int m = 0; m < 2; ++m) {
      float keep = b1 ? a4[2 * m + 1] : a4[2 * m];
      float send = b1 ? a4[2 * m]     : a4[2 * m + 1];
      a2[m] = keep + __shfl_xor(send, 16, 64);
    }
    {
      float keep = b2 ? a2[1] : a2[0];
      float send = b2 ? a2[0] : a2[1];
      v = keep + __shfl_xor(send, 32, 64);
    }
    xp[wave][t]                  = ygv;
    xp[wave][64 + (sub * 8 + g)] = (_Float16)(-dv * v);
  }
  __syncthreads();

  // ---- Phase 2: MFMA (B fragments from global W^T) ----
  constexpr int NW = COUT / 16;
  const int nn   = t & 15;
  const int quad = t >> 4;
  if (wave < NW) {
    const int colg = wave * 16 + nn;
    float4v acc = {0.f, 0.f, 0.f, 0.f};
    #pragma unroll
    for (int ks = 0; ks < 4; ++ks) {
      half8 a  = *(const half8*)&xp[nn][quad * 8 + 32 * ks];
      half8 bb = *(const half8*)&wt[(size_t)colg * 128 + quad * 8 + 32 * ks];
      acc = __builtin_amdgcn_mfma_f32_16x16x32_f16(a, bb, acc, 0, 0, 0);
    }
    // ---- Phase 3: epilogue ----
    const float bias = b[colg];
    #pragma unroll
    for (int rg = 0; rg < 4; ++rg) {
      const int rl = quad * 4 + rg;
      const int rr = row0 + rl;
      if (rr < n) {
        float v = acc[rg] + bias;
        if (RELU) v = fmaxf(v, 0.0f);
        if (DROPN) {
          if (drop_keep(nk0, nk1, (uint32_t)(rr * 64 + colg))) v *= 2.5f;
          else v = 0.0f;
        }
        if (WBF) {
          outb[(size_t)rr * COUT + colg] = (_Float16)v;
          outs[(size_t)rr * COUT + colg] = (_Float16)(dis[rr] * v);
        } else {
          outf[(size_t)rr * COUT + colg] = v;
        }
      }
    }
  }
}

extern "C" void kernel_launch(void* const* d_in, const int* in_sizes, int n_in,
                              void* d_out, int out_size, void* d_ws, size_t ws_size,
                              hipStream_t stream) {
  const float* x   = (const float*)d_in[0];
  const int*   ei  = (const int*)d_in[1];
  const float* W0  = (const float*)d_in[2];
  const float* b0  = (const float*)d_in[3];
  const float* W1f = (const float*)d_in[4];
  const float* b1  = (const float*)d_in[5];
  const float* W2  = (const float*)d_in[6];
  const float* b2  = (const float*)d_in[7];
  float* out = (float*)d_out;

  const int n = in_sizes[0] / 64;   // 50000
  const int e = in_sizes[1] / 2;    // 800000
  const int* row = ei;
  const int* col = ei + e;

  size_t off = 0;
  auto carve = [&](size_t elems) {   // elems in int32 units, 1KB-aligned
    size_t o = off;
    off += (elems + 255) & ~(size_t)255;
    return o;
  };
  int* base = (int*)d_ws;
  int*      cnt = base + carve(n);
  float*    dis = (float*)(base + carve(n));
  uint16_t* cs  = (uint16_t*)(base + carve((size_t)n * 32));       // n*64 u16
  _Float16* ya  = (_Float16*)(base + carve((size_t)n * 32));       // n*64 f16
  _Float16* ysa = (_Float16*)(base + carve((size_t)(n + 1) * 32)); // (n+1)*64 f16
  _Float16* yb  = (_Float16*)(base + carve((size_t)n * 32));
  _Float16* ysb = (_Float16*)(base + carve((size_t)(n + 1) * 32));
  _Float16* wh  = (_Float16*)(base + carve(10240));                // 20480 f16
  (void)ws_size;
  _Float16* wh0 = wh;            // [64][128]
  _Float16* wh1 = wh + 8192;     // [64][128]
  _Float16* wh2 = wh + 16384;    // [32][128]

  // dropout keys: fold_in(jax.random.key(1), i) = threefry2x32([0,1],[0,i])
  uint32_t dk[3][2];
  for (uint32_t i = 0; i < 3; ++i) tf2x32(0u, 1u, 0u, i, &dk[i][0], &dk[i][1]);

  hipMemsetAsync(cnt, 0, (size_t)n * 4, stream);

  const int nchunk = (e + 255) / 256;    // 3125
  const int bd = ((n * 64) + 255) / 256; // 12500
  const int bc = (n + 15) / 16;          // 3125
  const int rpx = (n + 7) / 8;           // rows per XCD slice (6250)

  k_fill2<<<nchunk * 8, 256, 0, stream>>>(row, col, cnt, cs, e, rpx);
  k_drop<<<bd, 256, 0, stream>>>(x, cnt, cs, dis, ya, ysa, ysb,
                                 dk[0][0], dk[0][1], n, n * 64,
                                 W0, W1f, W2, wh);

  k_conv<64, true,  true,  true ><<<bc, 1024, 0, stream>>>(
      ya, ysa, cnt, cs, dis, wh0, b0, nullptr, yb, ysb, dk[1][0], dk[1][1], n);
  k_conv<64, true,  true,  true ><<<bc, 1024, 0, stream>>>(
      yb, ysb, cnt, cs, dis, wh1, b1, nullptr, ya, ysa, dk[2][0], dk[2][1], n);
  k_conv<32, false, false, false><<<bc, 1024, 0, stream>>>(
      ya, ysa, cnt, cs, dis, wh2, b2, out, nullptr, nullptr, 0u, 0u, n);
}

// Round 3
// 197.534 us; speedup vs baseline: 2.0365x; 1.0349x over previous
//
#include <hip/hip_runtime.h>
#include <stdint.h>

typedef _Float16 half8 __attribute__((ext_vector_type(8)));
typedef float float4v __attribute__((ext_vector_type(4)));

__host__ __device__ inline void tf2x32(uint32_t k0, uint32_t k1,
                                       uint32_t x0, uint32_t x1,
                                       uint32_t* o0, uint32_t* o1) {
  const uint32_t ks2 = k0 ^ k1 ^ 0x1BD11BDAu;
#define ROTL(v, s) (((v) << (s)) | ((v) >> (32 - (s))))
#define RND(r) do { x0 += x1; x1 = ROTL(x1, r); x1 ^= x0; } while (0)
  x0 += k0; x1 += k1;
  RND(13); RND(15); RND(26); RND(6);
  x0 += k1; x1 += ks2 + 1u;
  RND(17); RND(29); RND(16); RND(24);
  x0 += ks2; x1 += k0 + 2u;
  RND(13); RND(15); RND(26); RND(6);
  x0 += k0; x1 += k1 + 3u;
  RND(17); RND(29); RND(16); RND(24);
  x0 += k1; x1 += ks2 + 4u;
  RND(13); RND(15); RND(26); RND(6);
  x0 += ks2; x1 += k0 + 5u;
  *o0 = x0; *o1 = x1;
#undef RND
#undef ROTL
}

__device__ inline bool drop_keep(uint32_t k0, uint32_t k1, uint32_t idx) {
  uint32_t o0, o1;
  tf2x32(k0, k1, 0u, idx, &o0, &o1);
  uint32_t bits = o0 ^ o1;
  float u = __uint_as_float((bits >> 9) | 0x3f800000u) - 1.0f;
  return u < 0.4f;
}

// XCD-owned slotted-CSR fill (R9-proven).
__global__ void k_fill2(const int* __restrict__ row, const int* __restrict__ col,
                        int* __restrict__ cnt, uint16_t* __restrict__ cs,
                        int e, int rows_per_xcd) {
  const int owner = blockIdx.x & 7;
  const int i = (blockIdx.x >> 3) * 256 + threadIdx.x;
  if (i < e) {
    int r = row[i];
    if (r / rows_per_xcd == owner) {
      int pos = atomicAdd(&cnt[r], 1);
      if (pos < 64) cs[(r << 6) + pos] = (uint16_t)col[i];
    }
  }
}

// layer-0 dropout + dis + slot padding (to multiple of 8) + W -> f16 W^T.
__global__ void k_drop(const float* __restrict__ x, const int* __restrict__ cnt,
                       uint16_t* __restrict__ cs, float* __restrict__ dis,
                       _Float16* __restrict__ y, _Float16* __restrict__ ys,
                       _Float16* __restrict__ ysb, uint32_t k0, uint32_t k1,
                       int n, int nd,
                       const float* __restrict__ W0, const float* __restrict__ W1,
                       const float* __restrict__ W2, _Float16* __restrict__ wh) {
  int i = blockIdx.x * 256 + threadIdx.x;
  if (i < 20480) {
    int d = i;
    if (d < 8192) {
      int o = d >> 7, k = d & 127;
      wh[d] = (_Float16)W0[k * 64 + o];
    } else if (d < 16384) {
      int d1 = d - 8192, o = d1 >> 7, k = d1 & 127;
      wh[d] = (_Float16)W1[k * 64 + o];
    } else {
      int d2 = d - 16384, o = d2 >> 7, k = d2 & 127;
      wh[d] = (_Float16)W2[k * 32 + o];
    }
  }
  if (i < 64) {                        // zero dummy gather rows (index n)
    ys[((size_t)n << 6) + i]  = (_Float16)0.f;
    ysb[((size_t)n << 6) + i] = (_Float16)0.f;
  }
  if (i < nd) {
    const int r = i >> 6;
    const int t = i & 63;
    const int d = cnt[r];
    const float dis_r = (d > 0) ? rsqrtf((float)d) : 0.0f;
    float v = drop_keep(k0, k1, (uint32_t)i) ? x[i] * 2.5f : 0.0f;
    y[i]  = (_Float16)v;
    ys[i] = (_Float16)(dis_r * v);
    if (t == 0) dis[r] = dis_r;
    const int cn = d < 64 ? d : 64;
    const int rnd = (cn + 7) & ~7;
    if (t >= cn && t < rnd) cs[(r << 6) + t] = (uint16_t)n;  // pad slot
  }
}

// One batch-group of T*8 edges starting at slot jb*8: issue T half8 loads,
// then consume into acc in ascending-j order (same FP order as R14's T=8).
// Lane l = 8*g + sub loads bytes [sub*16, sub*16+16) of edge (jb+j)*8+g's row.
// Register peak: hv[T] <= 16 VGPRs (T capped at 4 by callers) so the kernel
// fits the 64-VGPR cap of launch_bounds(256,8) without spilling (R15 lesson).
template<int T>
__device__ __forceinline__ void gatherT(int idx_all, int rnd, int jb, int g,
                                        int sub,
                                        const _Float16* __restrict__ ysg,
                                        uint32_t dummy, float acc[8]) {
  half8 hv[T];
  #pragma unroll
  for (int j = 0; j < T; ++j) {
    int sh = __shfl(idx_all, (jb + j) * 8 + g, 64);   // slot ((jb+j)*8+g)'s index
    uint32_t c = ((jb + j) * 8 < rnd) ? (uint32_t)(sh & 0xffff) : dummy;
    hv[j] = *(const half8*)((const char*)ysg + (c << 7) + (sub << 4));
  }
  #pragma unroll
  for (int j = 0; j < T; ++j)
    #pragma unroll
    for (int k = 0; k < 8; ++k) acc[k] += (float)hv[j][k];
}

// Fused conv. Block = 4 waves, 16 rows, 4 rows/wave sequential (R14 shape —
// best balanced: all 4 waves participate in MFMA phase, 8 blocks/CU stagger).
// R17 change vs R14: __launch_bounds__(256, 8) -> 32 waves/CU (HW max, was
// 24); deg>32 tail takes two sequential gatherT<4> passes (identical FP
// order) so the register peak (~50) fits the 64-VGPR cap without spilling.
// Phase 1: 8-edges-per-dwordx4 gather with per-row issue+consume, prologue
//   loads (cs line, cnt, dis, y-row) for all 4 rows hoisted; per-row
//   reduction via 3-step shfl_xor halving butterfly (keep/send cndmask
//   pairs -> fixed registers, no LDS, no barriers). Lane t ends with
//   feature (t&7)*8+(t>>3)'s full sum and writes that permuted xp column.
// Phase 2: MFMA 16x16x32_f16; A = [y|p] LDS tile, B = global f16 W^T.
// Phase 3: epilogue: +bias, relu, next-layer dropout; dual store y / ys.
template<int COUT, bool RELU, bool DROPN, bool WBF>
__global__ __launch_bounds__(256, 8) void k_conv(
    const _Float16* __restrict__ yg, const _Float16* __restrict__ ysg,
    const int* __restrict__ cnt, const uint16_t* __restrict__ cs,
    const float* __restrict__ dis, const _Float16* __restrict__ wt,
    const float* __restrict__ b, float* __restrict__ outf,
    _Float16* __restrict__ outb, _Float16* __restrict__ outs,
    uint32_t nk0, uint32_t nk1, int n) {
  constexpr int R  = 16;
  constexpr int TS = 136;
  __shared__ __align__(16) _Float16 xp[R][TS];

  const int wave = threadIdx.x >> 6;
  const int t    = threadIdx.x & 63;
  const int row0 = blockIdx.x * R;
  const int g    = t >> 3;
  const int sub  = t & 7;
  const uint32_t dummy = (uint32_t)n;

  // ---- Phase 1 prologue: all 4 rows' loads issued up front ----
  int      idxs[4], ds4[4];
  float    dv4[4];
  _Float16 ygv[4];
  #pragma unroll
  for (int i = 0; i < 4; ++i) {
    int r = row0 + wave * 4 + i;
    r = r < n ? r : n - 1;                       // clamp (grid is exact anyway)
    idxs[i] = cs[(r << 6) + t];                  // coalesced 128B slot line
    ds4[i]  = cnt[r];                            // wave-uniform
    dv4[i]  = dis[r];
    ygv[i]  = yg[(uint32_t)(r << 6) + t];
  }

  // ---- Phase 1: per-row gather + butterfly reduction ----
  #pragma unroll
  for (int i = 0; i < 4; ++i) {
    const int cn  = ds4[i] < 64 ? ds4[i] : 64;
    const int rnd = (cn + 7) & ~7;               // wave-uniform branch
    float acc[8] = {0.f, 0.f, 0.f, 0.f, 0.f, 0.f, 0.f, 0.f};
    if (rnd <= 16) {
      gatherT<2>(idxs[i], rnd, 0, g, sub, ysg, dummy, acc);
    } else if (rnd <= 32) {
      gatherT<4>(idxs[i], rnd, 0, g, sub, ysg, dummy, acc);
    } else {                                     // rare tail (deg > 32)
      gatherT<4>(idxs[i], rnd, 0, g, sub, ysg, dummy, acc);
      gatherT<4>(idxs[i], rnd, 4, g, sub, ysg, dummy, acc);
    }

    // halving butterfly over g bits (lane bits 3..5): lane ends with the
    // full sum of acc element g. keep/send selected by g's bit per step.
    const bool b0 = (g & 1), b1 = (g & 2), b2 = (g & 4);
    float a4[4], a2[2], v;
    #pragma unroll
    for (int m = 0; m < 4; ++m) {
      float keep = b0 ? acc[2 * m + 1] : acc[2 * m];
      float send = b0 ? acc[2 * m]     : acc[2 * m + 1];
      a4[m] = keep + __shfl_xor(send, 8, 64);
    }
    #pragma unroll
    for (int m = 0; m < 2; ++m) {
      float keep = b1 ? a4[2 * m + 1] : a4[2 * m];
      float send = b1 ? a4[2 * m]     : a4[2 * m + 1];
      a2[m] = keep + __shfl_xor(send, 16, 64);
    }
    {
      float keep = b2 ? a2[1] : a2[0];
      float send = b2 ? a2[0] : a2[1];
      v = keep + __shfl_xor(send, 32, 64);
    }
    const int rl = wave * 4 + i;
    xp[rl][t]                    = ygv[i];
    xp[rl][64 + (sub * 8 + g)]   = (_Float16)(-dv4[i] * v);
  }
  __syncthreads();

  // ---- Phase 2: MFMA (B fragments from global W^T) ----
  constexpr int NW = COUT / 16;
  const int nn   = t & 15;
  const int quad = t >> 4;
  if (wave < NW) {
    const int colg = wave * 16 + nn;
    float4v acc = {0.f, 0.f, 0.f, 0.f};
    #pragma unroll
    for (int ks = 0; ks < 4; ++ks) {
      half8 a  = *(const half8*)&xp[nn][quad * 8 + 32 * ks];
      half8 bb = *(const half8*)&wt[(size_t)colg * 128 + quad * 8 + 32 * ks];
      acc = __builtin_amdgcn_mfma_f32_16x16x32_f16(a, bb, acc, 0, 0, 0);
    }
    // ---- Phase 3: epilogue ----
    const float bias = b[colg];
    #pragma unroll
    for (int rg = 0; rg < 4; ++rg) {
      const int rl = quad * 4 + rg;
      const int rr = row0 + rl;
      if (rr < n) {
        float v = acc[rg] + bias;
        if (RELU) v = fmaxf(v, 0.0f);
        if (DROPN) {
          if (drop_keep(nk0, nk1, (uint32_t)(rr * 64 + colg))) v *= 2.5f;
          else v = 0.0f;
        }
        if (WBF) {
          outb[(size_t)rr * COUT + colg] = (_Float16)v;
          outs[(size_t)rr * COUT + colg] = (_Float16)(dis[rr] * v);
        } else {
          outf[(size_t)rr * COUT + colg] = v;
        }
      }
    }
  }
}

extern "C" void kernel_launch(void* const* d_in, const int* in_sizes, int n_in,
                              void* d_out, int out_size, void* d_ws, size_t ws_size,
                              hipStream_t stream) {
  const float* x   = (const float*)d_in[0];
  const int*   ei  = (const int*)d_in[1];
  const float* W0  = (const float*)d_in[2];
  const float* b0  = (const float*)d_in[3];
  const float* W1f = (const float*)d_in[4];
  const float* b1  = (const float*)d_in[5];
  const float* W2  = (const float*)d_in[6];
  const float* b2  = (const float*)d_in[7];
  float* out = (float*)d_out;

  const int n = in_sizes[0] / 64;   // 50000
  const int e = in_sizes[1] / 2;    // 800000
  const int* row = ei;
  const int* col = ei + e;

  size_t off = 0;
  auto carve = [&](size_t elems) {   // elems in int32 units, 1KB-aligned
    size_t o = off;
    off += (elems + 255) & ~(size_t)255;
    return o;
  };
  int* base = (int*)d_ws;
  int*      cnt = base + carve(n);
  float*    dis = (float*)(base + carve(n));
  uint16_t* cs  = (uint16_t*)(base + carve((size_t)n * 32));       // n*64 u16
  _Float16* ya  = (_Float16*)(base + carve((size_t)n * 32));       // n*64 f16
  _Float16* ysa = (_Float16*)(base + carve((size_t)(n + 1) * 32)); // (n+1)*64 f16
  _Float16* yb  = (_Float16*)(base + carve((size_t)n * 32));
  _Float16* ysb = (_Float16*)(base + carve((size_t)(n + 1) * 32));
  _Float16* wh  = (_Float16*)(base + carve(10240));                // 20480 f16
  (void)ws_size;
  _Float16* wh0 = wh;            // [64][128]
  _Float16* wh1 = wh + 8192;     // [64][128]
  _Float16* wh2 = wh + 16384;    // [32][128]

  // dropout keys: fold_in(jax.random.key(1), i) = threefry2x32([0,1],[0,i])
  uint32_t dk[3][2];
  for (uint32_t i = 0; i < 3; ++i) tf2x32(0u, 1u, 0u, i, &dk[i][0], &dk[i][1]);

  hipMemsetAsync(cnt, 0, (size_t)n * 4, stream);

  const int nchunk = (e + 255) / 256;    // 3125
  const int bd = ((n * 64) + 255) / 256; // 12500
  const int bc = (n + 15) / 16;          // 3125
  const int rpx = (n + 7) / 8;           // rows per XCD slice (6250)

  k_fill2<<<nchunk * 8, 256, 0, stream>>>(row, col, cnt, cs, e, rpx);
  k_drop<<<bd, 256, 0, stream>>>(x, cnt, cs, dis, ya, ysa, ysb,
                                 dk[0][0], dk[0][1], n, n * 64,
                                 W0, W1f, W2, wh);

  k_conv<64, true,  true,  true ><<<bc, 256, 0, stream>>>(
      ya, ysa, cnt, cs, dis, wh0, b0, nullptr, yb, ysb, dk[1][0], dk[1][1], n);
  k_conv<64, true,  true,  true ><<<bc, 256, 0, stream>>>(
      yb, ysb, cnt, cs, dis, wh1, b1, nullptr, ya, ysa, dk[2][0], dk[2][1], n);
  k_conv<32, false, false, false><<<bc, 256, 0, stream>>>(
      ya, ysa, cnt, cs, dis, wh2, b2, out, nullptr, nullptr, 0u, 0u, n);
}

// Round 4
// 192.633 us; speedup vs baseline: 2.0883x; 1.0254x over previous
//
#include <hip/hip_runtime.h>
#include <stdint.h>

typedef _Float16 half8 __attribute__((ext_vector_type(8)));
typedef float float4v __attribute__((ext_vector_type(4)));

__host__ __device__ inline void tf2x32(uint32_t k0, uint32_t k1,
                                       uint32_t x0, uint32_t x1,
                                       uint32_t* o0, uint32_t* o1) {
  const uint32_t ks2 = k0 ^ k1 ^ 0x1BD11BDAu;
#define ROTL(v, s) (((v) << (s)) | ((v) >> (32 - (s))))
#define RND(r) do { x0 += x1; x1 = ROTL(x1, r); x1 ^= x0; } while (0)
  x0 += k0; x1 += k1;
  RND(13); RND(15); RND(26); RND(6);
  x0 += k1; x1 += ks2 + 1u;
  RND(17); RND(29); RND(16); RND(24);
  x0 += ks2; x1 += k0 + 2u;
  RND(13); RND(15); RND(26); RND(6);
  x0 += k0; x1 += k1 + 3u;
  RND(17); RND(29); RND(16); RND(24);
  x0 += k1; x1 += ks2 + 4u;
  RND(13); RND(15); RND(26); RND(6);
  x0 += ks2; x1 += k0 + 5u;
  *o0 = x0; *o1 = x1;
#undef RND
#undef ROTL
}

__device__ inline bool drop_keep(uint32_t k0, uint32_t k1, uint32_t idx) {
  uint32_t o0, o1;
  tf2x32(k0, k1, 0u, idx, &o0, &o1);
  uint32_t bits = o0 ^ o1;
  float u = __uint_as_float((bits >> 9) | 0x3f800000u) - 1.0f;
  return u < 0.4f;
}

// XCD-owned slotted-CSR fill (R9-proven).
__global__ void k_fill2(const int* __restrict__ row, const int* __restrict__ col,
                        int* __restrict__ cnt, uint16_t* __restrict__ cs,
                        int e, int rows_per_xcd) {
  const int owner = blockIdx.x & 7;
  const int i = (blockIdx.x >> 3) * 256 + threadIdx.x;
  if (i < e) {
    int r = row[i];
    if (r / rows_per_xcd == owner) {
      int pos = atomicAdd(&cnt[r], 1);
      if (pos < 64) cs[(r << 6) + pos] = (uint16_t)col[i];
    }
  }
}

// layer-0 dropout + dis + slot padding (to multiple of 8) + W -> f16 W^T.
__global__ void k_drop(const float* __restrict__ x, const int* __restrict__ cnt,
                       uint16_t* __restrict__ cs, float* __restrict__ dis,
                       _Float16* __restrict__ y, _Float16* __restrict__ ys,
                       _Float16* __restrict__ ysb, uint32_t k0, uint32_t k1,
                       int n, int nd,
                       const float* __restrict__ W0, const float* __restrict__ W1,
                       const float* __restrict__ W2, _Float16* __restrict__ wh) {
  int i = blockIdx.x * 256 + threadIdx.x;
  if (i < 20480) {
    int d = i;
    if (d < 8192) {
      int o = d >> 7, k = d & 127;
      wh[d] = (_Float16)W0[k * 64 + o];
    } else if (d < 16384) {
      int d1 = d - 8192, o = d1 >> 7, k = d1 & 127;
      wh[d] = (_Float16)W1[k * 64 + o];
    } else {
      int d2 = d - 16384, o = d2 >> 7, k = d2 & 127;
      wh[d] = (_Float16)W2[k * 32 + o];
    }
  }
  if (i < 64) {                        // zero dummy gather rows (index n)
    ys[((size_t)n << 6) + i]  = (_Float16)0.f;
    ysb[((size_t)n << 6) + i] = (_Float16)0.f;
  }
  if (i < nd) {
    const int r = i >> 6;
    const int t = i & 63;
    const int d = cnt[r];
    const float dis_r = (d > 0) ? rsqrtf((float)d) : 0.0f;
    float v = drop_keep(k0, k1, (uint32_t)i) ? x[i] * 2.5f : 0.0f;
    y[i]  = (_Float16)v;
    ys[i] = (_Float16)(dis_r * v);
    if (t == 0) dis[r] = dis_r;
    const int cn = d < 64 ? d : 64;
    const int rnd = (cn + 7) & ~7;
    if (t >= cn && t < rnd) cs[(r << 6) + t] = (uint16_t)n;  // pad slot
  }
}

// Issue one batch of 4x8 edges' loads into hv[0..3] (constant-indexed ->
// registers). Lane l = 8*g + sub loads bytes [sub*16, sub*16+16) of edge
// (jb+j)*8+g's row. Batches past rnd load the zero dummy row (single hot
// 128B line, broadcast-coalesced -> ~free) so the pipeline shape is static.
__device__ __forceinline__ void issue4(int idx_all, int rnd, int jb, int g,
                                       int sub,
                                       const _Float16* __restrict__ ysg,
                                       uint32_t dummy, half8 hv[4]) {
  #pragma unroll
  for (int j = 0; j < 4; ++j) {
    int sh = __shfl(idx_all, (jb + j) * 8 + g, 64);   // slot ((jb+j)*8+g)'s index
    uint32_t c = ((jb + j) * 8 < rnd) ? (uint32_t)(sh & 0xffff) : dummy;
    hv[j] = *(const half8*)((const char*)ysg + (c << 7) + (sub << 4));
  }
}

// Ascending-j, ascending-k adds: same FP order as R14/R17's gatherT; dummy
// batches contribute +0.0f (inert).
__device__ __forceinline__ void consume4(const half8 hv[4], float acc[8]) {
  #pragma unroll
  for (int j = 0; j < 4; ++j)
    #pragma unroll
    for (int k = 0; k < 8; ++k) acc[k] += (float)hv[j][k];
}

// Fused conv. Block = 4 waves, 16 rows, 4 rows/wave (R14 shape).
// R18 change: 4-ROW-DEEP REGISTER PIPELINE. All 4 rows' gather batches
// (4 x 4 x 16B lines = 16 lines/wave) are issued back-to-back into four
// NAMED half8 arrays before any consumption -> one gather-latency wall per
// wave instead of four, ~4x in-flight lines. Register budget by design:
// 64 VGPR staging + ~50 misc < 128 cap from __launch_bounds__(256,4)
// (R15's spill was at cap ~85 with the same staging). Occupancy drops to
// 16 waves/CU -- acceptable: R17 proved wave count is not the constraint.
// deg>32 tail (Poisson(16) tail, ~7 rows of 50k) issues+consumes a second
// batch serially reusing the same hv regs (identical FP order to R17).
// Phase 1 reduction: 3-step shfl_xor halving butterfly (keep/send cndmask
//   pairs -> fixed registers, no LDS, no barriers). Lane t ends with
//   feature (t&7)*8+(t>>3)'s full sum and writes that permuted xp column.
// Phase 2: MFMA 16x16x32_f16; A = [y|p] LDS tile, B = global f16 W^T.
// Phase 3: epilogue: +bias, relu, next-layer dropout; dual store y / ys.
template<int COUT, bool RELU, bool DROPN, bool WBF>
__global__ __launch_bounds__(256, 4) void k_conv(
    const _Float16* __restrict__ yg, const _Float16* __restrict__ ysg,
    const int* __restrict__ cnt, const uint16_t* __restrict__ cs,
    const float* __restrict__ dis, const _Float16* __restrict__ wt,
    const float* __restrict__ b, float* __restrict__ outf,
    _Float16* __restrict__ outb, _Float16* __restrict__ outs,
    uint32_t nk0, uint32_t nk1, int n) {
  constexpr int R  = 16;
  constexpr int TS = 136;
  __shared__ __align__(16) _Float16 xp[R][TS];

  const int wave = threadIdx.x >> 6;
  const int t    = threadIdx.x & 63;
  const int row0 = blockIdx.x * R;
  const int g    = t >> 3;
  const int sub  = t & 7;
  const uint32_t dummy = (uint32_t)n;

  // ---- Phase 1 prologue: all 4 rows' metadata loads issued up front ----
  int      idxs[4], rnd4[4];
  float    dv4[4];
  #pragma unroll
  for (int i = 0; i < 4; ++i) {
    int r = row0 + wave * 4 + i;
    r = r < n ? r : n - 1;                       // clamp (grid is exact anyway)
    idxs[i] = cs[(r << 6) + t];                  // coalesced 128B slot line
    const int d = cnt[r];                        // wave-uniform
    dv4[i]  = dis[r];
    const int cn = d < 64 ? d : 64;
    rnd4[i] = (cn + 7) & ~7;
    // y half of the A-tile: write now, frees the register immediately.
    xp[wave * 4 + i][t] = yg[(uint32_t)(r << 6) + t];
  }

  // ---- Phase 1a: issue ALL 4 rows' gather batches (16 lines in flight) ----
  half8 hv0[4], hv1[4], hv2[4], hv3[4];
  issue4(idxs[0], rnd4[0], 0, g, sub, ysg, dummy, hv0);
  issue4(idxs[1], rnd4[1], 0, g, sub, ysg, dummy, hv1);
  issue4(idxs[2], rnd4[2], 0, g, sub, ysg, dummy, hv2);
  issue4(idxs[3], rnd4[3], 0, g, sub, ysg, dummy, hv3);
  __builtin_amdgcn_sched_barrier(0);   // keep all issues above all consumes

  // ---- Phase 1b: per-row consume + butterfly reduction ----
  #pragma unroll
  for (int i = 0; i < 4; ++i) {
    half8* hv = (i == 0) ? hv0 : (i == 1) ? hv1 : (i == 2) ? hv2 : hv3;
    float acc[8] = {0.f, 0.f, 0.f, 0.f, 0.f, 0.f, 0.f, 0.f};
    consume4(hv, acc);
    if (rnd4[i] > 32) {                          // rare tail (deg > 32)
      issue4(idxs[i], rnd4[i], 4, g, sub, ysg, dummy, hv);
      consume4(hv, acc);
    }

    // halving butterfly over g bits (lane bits 3..5): lane ends with the
    // full sum of acc element g. keep/send selected by g's bit per step.
    const bool b0 = (g & 1), b1 = (g & 2), b2 = (g & 4);
    float a4[4], a2[2], v;
    #pragma unroll
    for (int m = 0; m < 4; ++m) {
      float keep = b0 ? acc[2 * m + 1] : acc[2 * m];
      float send = b0 ? acc[2 * m]     : acc[2 * m + 1];
      a4[m] = keep + __shfl_xor(send, 8, 64);
    }
    #pragma unroll
    for (int m = 0; m < 2; ++m) {
      float keep = b1 ? a4[2 * m + 1] : a4[2 * m];
      float send = b1 ? a4[2 * m]     : a4[2 * m + 1];
      a2[m] = keep + __shfl_xor(send, 16, 64);
    }
    {
      float keep = b2 ? a2[1] : a2[0];
      float send = b2 ? a2[0] : a2[1];
      v = keep + __shfl_xor(send, 32, 64);
    }
    xp[wave * 4 + i][64 + (sub * 8 + g)] = (_Float16)(-dv4[i] * v);
  }
  __syncthreads();

  // ---- Phase 2: MFMA (B fragments from global W^T) ----
  constexpr int NW = COUT / 16;
  const int nn   = t & 15;
  const int quad = t >> 4;
  if (wave < NW) {
    const int colg = wave * 16 + nn;
    float4v acc = {0.f, 0.f, 0.f, 0.f};
    #pragma unroll
    for (int ks = 0; ks < 4; ++ks) {
      half8 a  = *(const half8*)&xp[nn][quad * 8 + 32 * ks];
      half8 bb = *(const half8*)&wt[(size_t)colg * 128 + quad * 8 + 32 * ks];
      acc = __builtin_amdgcn_mfma_f32_16x16x32_f16(a, bb, acc, 0, 0, 0);
    }
    // ---- Phase 3: epilogue ----
    const float bias = b[colg];
    #pragma unroll
    for (int rg = 0; rg < 4; ++rg) {
      const int rl = quad * 4 + rg;
      const int rr = row0 + rl;
      if (rr < n) {
        float v = acc[rg] + bias;
        if (RELU) v = fmaxf(v, 0.0f);
        if (DROPN) {
          if (drop_keep(nk0, nk1, (uint32_t)(rr * 64 + colg))) v *= 2.5f;
          else v = 0.0f;
        }
        if (WBF) {
          outb[(size_t)rr * COUT + colg] = (_Float16)v;
          outs[(size_t)rr * COUT + colg] = (_Float16)(dis[rr] * v);
        } else {
          outf[(size_t)rr * COUT + colg] = v;
        }
      }
    }
  }
}

extern "C" void kernel_launch(void* const* d_in, const int* in_sizes, int n_in,
                              void* d_out, int out_size, void* d_ws, size_t ws_size,
                              hipStream_t stream) {
  const float* x   = (const float*)d_in[0];
  const int*   ei  = (const int*)d_in[1];
  const float* W0  = (const float*)d_in[2];
  const float* b0  = (const float*)d_in[3];
  const float* W1f = (const float*)d_in[4];
  const float* b1  = (const float*)d_in[5];
  const float* W2  = (const float*)d_in[6];
  const float* b2  = (const float*)d_in[7];
  float* out = (float*)d_out;

  const int n = in_sizes[0] / 64;   // 50000
  const int e = in_sizes[1] / 2;    // 800000
  const int* row = ei;
  const int* col = ei + e;

  size_t off = 0;
  auto carve = [&](size_t elems) {   // elems in int32 units, 1KB-aligned
    size_t o = off;
    off += (elems + 255) & ~(size_t)255;
    return o;
  };
  int* base = (int*)d_ws;
  int*      cnt = base + carve(n);
  float*    dis = (float*)(base + carve(n));
  uint16_t* cs  = (uint16_t*)(base + carve((size_t)n * 32));       // n*64 u16
  _Float16* ya  = (_Float16*)(base + carve((size_t)n * 32));       // n*64 f16
  _Float16* ysa = (_Float16*)(base + carve((size_t)(n + 1) * 32)); // (n+1)*64 f16
  _Float16* yb  = (_Float16*)(base + carve((size_t)n * 32));
  _Float16* ysb = (_Float16*)(base + carve((size_t)(n + 1) * 32));
  _Float16* wh  = (_Float16*)(base + carve(10240));                // 20480 f16
  (void)ws_size;
  _Float16* wh0 = wh;            // [64][128]
  _Float16* wh1 = wh + 8192;     // [64][128]
  _Float16* wh2 = wh + 16384;    // [32][128]

  // dropout keys: fold_in(jax.random.key(1), i) = threefry2x32([0,1],[0,i])
  uint32_t dk[3][2];
  for (uint32_t i = 0; i < 3; ++i) tf2x32(0u, 1u, 0u, i, &dk[i][0], &dk[i][1]);

  hipMemsetAsync(cnt, 0, (size_t)n * 4, stream);

  const int nchunk = (e + 255) / 256;    // 3125
  const int bd = ((n * 64) + 255) / 256; // 12500
  const int bc = (n + 15) / 16;          // 3125
  const int rpx = (n + 7) / 8;           // rows per XCD slice (6250)

  k_fill2<<<nchunk * 8, 256, 0, stream>>>(row, col, cnt, cs, e, rpx);
  k_drop<<<bd, 256, 0, stream>>>(x, cnt, cs, dis, ya, ysa, ysb,
                                 dk[0][0], dk[0][1], n, n * 64,
                                 W0, W1f, W2, wh);

  k_conv<64, true,  true,  true ><<<bc, 256, 0, stream>>>(
      ya, ysa, cnt, cs, dis, wh0, b0, nullptr, yb, ysb, dk[1][0], dk[1][1], n);
  k_conv<64, true,  true,  true ><<<bc, 256, 0, stream>>>(
      yb, ysb, cnt, cs, dis, wh1, b1, nullptr, ya, ysa, dk[2][0], dk[2][1], n);
  k_conv<32, false, false, false><<<bc, 256, 0, stream>>>(
      ya, ysa, cnt, cs, dis, wh2, b2, out, nullptr, nullptr, 0u, 0u, n);
}